// Round 4
// baseline (635.975 us; speedup 1.0000x reference)
//
#include <hip/hip_runtime.h>
#include <math.h>

#define BB 32
#define LL 512
#define DD 512
#define NH 8
#define HD 64

typedef __attribute__((ext_vector_type(8))) short bf16x8;
typedef __attribute__((ext_vector_type(4))) float f32x4;

__device__ __forceinline__ unsigned short f2bf(float x) {
    union { float f; unsigned u; } v; v.f = x;
    unsigned r = v.u + 0x7fffu + ((v.u >> 16) & 1u);  // RNE
    return (unsigned short)(r >> 16);
}

// ---------------- reductions ----------------
__device__ __forceinline__ float warp_sum(float v) {
    #pragma unroll
    for (int o = 32; o > 0; o >>= 1) v += __shfl_down(v, o);
    return v;
}

// ---------------- LayerNorm: one block per row of 512, bf16 out ----------------
__global__ void ln_kernel(const float* __restrict__ X, const float* __restrict__ g,
                          const float* __restrict__ b, unsigned short* __restrict__ Y) {
    __shared__ float red[8];
    const size_t base = (size_t)blockIdx.x * DD;
    const int t = threadIdx.x;
    float x0 = X[base + t], x1 = X[base + t + 256];
    float s = warp_sum(x0 + x1);
    float q = warp_sum(x0 * x0 + x1 * x1);
    if ((t & 63) == 0) { red[t >> 6] = s; red[4 + (t >> 6)] = q; }
    __syncthreads();
    float S = red[0] + red[1] + red[2] + red[3];
    float Q = red[4] + red[5] + red[6] + red[7];
    float mu  = S * (1.0f / 512.0f);
    float var = Q * (1.0f / 512.0f) - mu * mu;
    float r = rsqrtf(var + 1e-5f);
    Y[base + t]       = f2bf((x0 - mu) * r * g[t] + b[t]);
    Y[base + t + 256] = f2bf((x1 - mu) * r * g[t + 256] + b[t + 256]);
}

// ---------------- weight transpose + bf16 cast: W (K x N) -> WT (N x K) ----------------
__global__ void transpose_bf16(const float* __restrict__ W, unsigned short* __restrict__ WT,
                               int K, int N) {
    __shared__ float t[32][33];
    const int n0 = blockIdx.x * 32, k0 = blockIdx.y * 32;
    const int tx = threadIdx.x & 31, ty = threadIdx.x >> 5;
    #pragma unroll
    for (int r = 0; r < 32; r += 8)
        t[ty + r][tx] = W[(size_t)(k0 + ty + r) * N + n0 + tx];
    __syncthreads();
    #pragma unroll
    for (int r = 0; r < 32; r += 8)
        WT[(size_t)(n0 + ty + r) * K + k0 + tx] = f2bf(t[tx][ty + r]);
}

// ---------------- bf16 MFMA GEMM ----------------
// A: M x K bf16 row-major; BT: N x K bf16 row-major. 128x128 tile, BK=64.
// OM: 0 = f32 out, 1 = bf16 out,
//     2 = qkv split: Q -> Cv row-major [row][512]; K -> kfrag blobs; V -> vfrag blobs.
// Fragment blob layout (1 KB each): idx [b][h][kt][kk][j], element (lane*8 + e)
//   K: lane=hi*16+lo holds K[kpos=kt*64+j*16+lo][d=kk*32+hi*8+e]
//   V: lane=hi*16+lo holds V[d=j*16+lo][kpos=kt*64+kk*32+hi*8+e]
template <int ACT, int RES, int OM>
__global__ __launch_bounds__(256)
void gemm_mfma(const unsigned short* __restrict__ A, const unsigned short* __restrict__ BT,
               const float* __restrict__ bias, const float* __restrict__ res,
               void* __restrict__ Cv, unsigned short* __restrict__ kfrag,
               unsigned short* __restrict__ vfrag, int M, int N, int K) {
    __shared__ unsigned short As[128 * 64];
    __shared__ unsigned short Bs[128 * 64];
    const int tid = threadIdx.x;
    const int wave = tid >> 6, lane = tid & 63;
    const int wm = (wave >> 1) * 64, wn = (wave & 1) * 64;
    const int bm = blockIdx.y * 128, bn = blockIdx.x * 128;

    f32x4 acc[4][4] = {};

    for (int k0 = 0; k0 < K; k0 += 64) {
        __syncthreads();
        #pragma unroll
        for (int it = 0; it < 4; ++it) {
            const int s = it * 256 + tid;
            const int row = s >> 3, pch = s & 7;
            const int lch = pch ^ (row & 7);
            const unsigned short* ga = A + (size_t)(bm + row) * K + k0 + lch * 8;
            __builtin_amdgcn_global_load_lds(
                (const __attribute__((address_space(1))) void*)ga,
                (__attribute__((address_space(3))) void*)(As + s * 8), 16, 0, 0);
            const unsigned short* gb = BT + (size_t)(bn + row) * K + k0 + lch * 8;
            __builtin_amdgcn_global_load_lds(
                (const __attribute__((address_space(1))) void*)gb,
                (__attribute__((address_space(3))) void*)(Bs + s * 8), 16, 0, 0);
        }
        __syncthreads();
        #pragma unroll
        for (int ks = 0; ks < 2; ++ks) {
            bf16x8 af[4], bfr[4];
            #pragma unroll
            for (int i = 0; i < 4; ++i) {
                const int row = wm + i * 16 + (lane & 15);
                const int pch = (ks * 4 + (lane >> 4)) ^ (row & 7);
                af[i] = *(const bf16x8*)(As + row * 64 + pch * 8);
            }
            #pragma unroll
            for (int j = 0; j < 4; ++j) {
                const int row = wn + j * 16 + (lane & 15);
                const int pch = (ks * 4 + (lane >> 4)) ^ (row & 7);
                bfr[j] = *(const bf16x8*)(Bs + row * 64 + pch * 8);
            }
            #pragma unroll
            for (int i = 0; i < 4; ++i)
                #pragma unroll
                for (int j = 0; j < 4; ++j)
                    acc[i][j] = __builtin_amdgcn_mfma_f32_16x16x32_bf16(
                        af[i], bfr[j], acc[i][j], 0, 0, 0);
        }
    }

    const int cl = lane & 15, rq = (lane >> 4) * 4;
    #pragma unroll
    for (int j = 0; j < 4; ++j) {
        const int col = bn + wn + j * 16 + cl;
        const float bv = bias[col];
        #pragma unroll
        for (int i = 0; i < 4; ++i) {
            const int r0 = bm + wm + i * 16 + rq;
            #pragma unroll
            for (int r = 0; r < 4; ++r) {
                float v = acc[i][j][r] + bv;
                if (ACT == 1) v = 0.5f * v * (1.0f + erff(v * 0.70710678118654752f));
                if (RES) v += res[(size_t)(r0 + r) * N + col];
                if (OM == 0) {
                    ((float*)Cv)[(size_t)(r0 + r) * N + col] = v;
                } else if (OM == 1) {
                    ((unsigned short*)Cv)[(size_t)(r0 + r) * N + col] = f2bf(v);
                } else {
                    const int row = r0 + r;
                    const int b = row >> 9, kpos = row & 511;
                    if (col < 512) {
                        ((unsigned short*)Cv)[(size_t)row * 512 + col] = f2bf(v);
                    } else if (col < 1024) {
                        const int h = (col - 512) >> 6, dd = (col - 512) & 63;
                        const int kt = kpos >> 6, jj = (kpos >> 4) & 3, lo2 = kpos & 15;
                        const int kk = dd >> 5, hi2 = (dd >> 3) & 3, e = dd & 7;
                        kfrag[((((size_t)(b * NH + h) * 8 + kt) * 2 + kk) * 4 + jj) * 512
                              + (hi2 * 16 + lo2) * 8 + e] = f2bf(v);
                    } else {
                        const int h = (col - 1024) >> 6, dd = (col - 1024) & 63;
                        const int kt = kpos >> 6, kk = (kpos >> 5) & 1, hi2 = (kpos >> 3) & 3, e = kpos & 7;
                        const int jj = dd >> 4, lo2 = dd & 15;
                        vfrag[((((size_t)(b * NH + h) * 8 + kt) * 2 + kk) * 4 + jj) * 512
                              + (hi2 * 16 + lo2) * 8 + e] = f2bf(v);
                    }
                }
            }
        }
    }
}

// ---------------- fused flash attention v5: per-head blocks, barrier-free ----------------
// grid: (h=8, qg=4, b=32) = 1024 blocks (exactly chip-resident), 512 thr = 8 waves.
// Each block: ONE head, 128 q-rows; wave w owns q-rows [qg*128+w*16, +16).
// v5 rationale (v4 was LDS-BW + barrier bound: 8 waves x 16KB bias reads/iter
// through LDS = 4MB/CU + 5.8M conflicts + per-iter barrier):
//  - bias read global->register per lane (float4; each byte once per wave).
//    inter (134MB) + frags + qbuf = 182MB fit ENTIRELY in 256MB L3, so the
//    8x h-axis amplification is served by L3/L2, never HBM (unlike v3, no
//    cross-wave sharing is needed, so wave drift is harmless).
//  - ZERO __syncthreads: no shared LDS state (plds is wave-private).
//  - K/V frag loads: all 8 waves read the SAME head's blobs -> L1 broadcast
//    (8x less L2 traffic than the all-heads-per-block layout).
//  - bias consumed in two j-halves to cap live VGPRs; launch_bounds(512,4)
//    pins VGPR<=128 -> 16 waves/CU, all independent.
//  - defer-max (T13): skip alpha-rescale when __all(mx - m <= 8); P <= e^8
//    is safe in bf16.
__global__ __launch_bounds__(512, 4)
void flash_kernel(const unsigned short* __restrict__ qbuf,
                  const unsigned short* __restrict__ kfrag,
                  const unsigned short* __restrict__ vfrag,
                  const float* __restrict__ inter,
                  const float* __restrict__ iw,
                  unsigned short* __restrict__ O) {
    __shared__ unsigned short plds[8][16 * 72];     // per-wave P tile
    const int h = blockIdx.x, qg = blockIdx.y, b = blockIdx.z;
    const int tid = threadIdx.x, wave = tid >> 6, lane = tid & 63;
    const int lo = lane & 15, hi = lane >> 4;
    const int q0 = qg * 128 + wave * 16;            // wave's q base

    const float iw0 = iw[h], iw1 = iw[8 + h], iw2 = iw[16 + h], iw3 = iw[24 + h];
    unsigned short* pw = &plds[wave][0];

    // per-lane bias row pointer: q = q0 + lo
    const float* bp = inter + ((size_t)(b * 512 + q0 + lo) * 512) * 4;

    // Q fragment: q-row = lo, d = kk*32 + hi*8 + e
    const unsigned short* qp = qbuf + ((size_t)(b * 512 + q0 + lo)) * 512 + h * 64 + hi * 8;
    const bf16x8 qf0 = *(const bf16x8*)(qp);
    const bf16x8 qf1 = *(const bf16x8*)(qp + 32);

    // fragment blob bases (kt stride = 2*4*512 u16 = 4096)
    const unsigned short* kfb = kfrag + (size_t)(b * NH + h) * 32768 + (size_t)lane * 8;
    const unsigned short* vfb = vfrag + (size_t)(b * NH + h) * 32768 + (size_t)lane * 8;

    f32x4 o[4] = {};
    float m = -1e30f, lsum = 0.0f;

    #pragma unroll 1
    for (int kt = 0; kt < 8; ++kt) {
        // (1) K fragments (8 x 1KB; identical addresses across the 8 waves -> L1)
        const unsigned short* kp = kfb + kt * 4096;
        bf16x8 kf[8];
        #pragma unroll
        for (int jj = 0; jj < 8; ++jj)
            kf[jj] = *(const bf16x8*)(kp + jj * 512);
        // (2) bias j=0,1 (8 float4, same latency cohort as kf)
        const float* bk = bp + (size_t)kt * 256;    // +kt*64 k-cols
        float4 c0[4], c1[4];
        #pragma unroll
        for (int r = 0; r < 4; ++r) c0[r] = *(const float4*)(bk + (hi * 4 + r) * 4);
        #pragma unroll
        for (int r = 0; r < 4; ++r) c1[r] = *(const float4*)(bk + (16 + hi * 4 + r) * 4);
        __builtin_amdgcn_sched_barrier(0);
        // (3) S^T = K Q^T : lane owns q = lo, k = j*16 + hi*4 + r
        f32x4 s4[4] = {};
        __builtin_amdgcn_s_setprio(1);
        #pragma unroll
        for (int j = 0; j < 4; ++j)
            s4[j] = __builtin_amdgcn_mfma_f32_16x16x32_bf16(kf[j], qf0, s4[j], 0, 0, 0);
        #pragma unroll
        for (int j = 0; j < 4; ++j)
            s4[j] = __builtin_amdgcn_mfma_f32_16x16x32_bf16(kf[4 + j], qf1, s4[j], 0, 0, 0);
        __builtin_amdgcn_s_setprio(0);
        __builtin_amdgcn_sched_barrier(0);
        // (4) V fragments (kf regs are dead; consumed at PV, latency covered)
        const unsigned short* vp = vfb + kt * 4096;
        bf16x8 vf[8];
        #pragma unroll
        for (int jj = 0; jj < 8; ++jj)
            vf[jj] = *(const bf16x8*)(vp + jj * 512);
        __builtin_amdgcn_sched_barrier(0);
        // (5) bias FMA j=0,1
        #pragma unroll
        for (int r = 0; r < 4; ++r)
            s4[0][r] = s4[0][r] * 0.125f + c0[r].x * iw0 + c0[r].y * iw1 + c0[r].z * iw2 + c0[r].w * iw3;
        #pragma unroll
        for (int r = 0; r < 4; ++r)
            s4[1][r] = s4[1][r] * 0.125f + c1[r].x * iw0 + c1[r].y * iw1 + c1[r].z * iw2 + c1[r].w * iw3;
        // (6) bias j=2,3 (issued after j01 regs die)
        float4 d0[4], d1[4];
        #pragma unroll
        for (int r = 0; r < 4; ++r) d0[r] = *(const float4*)(bk + (32 + hi * 4 + r) * 4);
        #pragma unroll
        for (int r = 0; r < 4; ++r) d1[r] = *(const float4*)(bk + (48 + hi * 4 + r) * 4);
        __builtin_amdgcn_sched_barrier(0);
        #pragma unroll
        for (int r = 0; r < 4; ++r)
            s4[2][r] = s4[2][r] * 0.125f + d0[r].x * iw0 + d0[r].y * iw1 + d0[r].z * iw2 + d0[r].w * iw3;
        #pragma unroll
        for (int r = 0; r < 4; ++r)
            s4[3][r] = s4[3][r] * 0.125f + d1[r].x * iw0 + d1[r].y * iw1 + d1[r].z * iw2 + d1[r].w * iw3;
        // (7) online softmax with defer-max; per-lane row q = lo
        float t0 = fmaxf(fmaxf(s4[0][0], s4[0][1]), fmaxf(s4[0][2], s4[0][3]));
        float t1 = fmaxf(fmaxf(s4[1][0], s4[1][1]), fmaxf(s4[1][2], s4[1][3]));
        float t2 = fmaxf(fmaxf(s4[2][0], s4[2][1]), fmaxf(s4[2][2], s4[2][3]));
        float t3 = fmaxf(fmaxf(s4[3][0], s4[3][1]), fmaxf(s4[3][2], s4[3][3]));
        float mx = fmaxf(fmaxf(t0, t1), fmaxf(t2, t3));
        mx = fmaxf(mx, __shfl_xor(mx, 16));
        mx = fmaxf(mx, __shfl_xor(mx, 32));
        if (!__all(mx - m <= 8.0f)) {               // rescale only when max grew
            const float mn = fmaxf(m, mx);
            const float al = __expf(m - mn);
            m = mn;
            lsum *= al;
            const float aR0 = __shfl(al, hi * 4 + 0);
            const float aR1 = __shfl(al, hi * 4 + 1);
            const float aR2 = __shfl(al, hi * 4 + 2);
            const float aR3 = __shfl(al, hi * 4 + 3);
            #pragma unroll
            for (int j2 = 0; j2 < 4; ++j2) {
                o[j2][0] *= aR0; o[j2][1] *= aR1; o[j2][2] *= aR2; o[j2][3] *= aR3;
            }
        }
        #pragma unroll
        for (int j = 0; j < 4; ++j)
            #pragma unroll
            for (int r = 0; r < 4; ++r)
                s4[j][r] = __expf(s4[j][r] - m);
        float u0 = (s4[0][0] + s4[0][1]) + (s4[0][2] + s4[0][3]);
        float u1 = (s4[1][0] + s4[1][1]) + (s4[1][2] + s4[1][3]);
        float u2 = (s4[2][0] + s4[2][1]) + (s4[2][2] + s4[2][3]);
        float u3 = (s4[3][0] + s4[3][1]) + (s4[3][2] + s4[3][3]);
        float ts = (u0 + u1) + (u2 + u3);
        ts += __shfl_xor(ts, 16);
        ts += __shfl_xor(ts, 32);
        lsum += ts;
        // (8) P -> LDS, packed b64, wave-private (no barrier)
        uint2* pq = (uint2*)(pw + lo * 72);
        #pragma unroll
        for (int j = 0; j < 4; ++j) {
            uint2 d;
            d.x = (unsigned)f2bf(s4[j][0]) | ((unsigned)f2bf(s4[j][1]) << 16);
            d.y = (unsigned)f2bf(s4[j][2]) | ((unsigned)f2bf(s4[j][3]) << 16);
            pq[j * 4 + hi] = d;
        }
        // (9) O += P V
        __builtin_amdgcn_s_setprio(1);
        #pragma unroll
        for (int kk = 0; kk < 2; ++kk) {
            const bf16x8 pf = *(const bf16x8*)(pw + lo * 72 + kk * 32 + hi * 8);
            #pragma unroll
            for (int j2 = 0; j2 < 4; ++j2)
                o[j2] = __builtin_amdgcn_mfma_f32_16x16x32_bf16(
                    pf, vf[kk * 4 + j2], o[j2], 0, 0, 0);
        }
        __builtin_amdgcn_s_setprio(0);
    }

    // ---- epilogue ----
    const float iR0 = 1.0f / __shfl(lsum, hi * 4 + 0);
    const float iR1 = 1.0f / __shfl(lsum, hi * 4 + 1);
    const float iR2 = 1.0f / __shfl(lsum, hi * 4 + 2);
    const float iR3 = 1.0f / __shfl(lsum, hi * 4 + 3);
    const int qC0 = q0 + hi * 4;
    #pragma unroll
    for (int j2 = 0; j2 < 4; ++j2) {
        O[(size_t)(b * 512 + qC0 + 0) * 512 + h * 64 + j2 * 16 + lo] = f2bf(o[j2][0] * iR0);
        O[(size_t)(b * 512 + qC0 + 1) * 512 + h * 64 + j2 * 16 + lo] = f2bf(o[j2][1] * iR1);
        O[(size_t)(b * 512 + qC0 + 2) * 512 + h * 64 + j2 * 16 + lo] = f2bf(o[j2][2] * iR2);
        O[(size_t)(b * 512 + qC0 + 3) * 512 + h * 64 + j2 * 16 + lo] = f2bf(o[j2][3] * iR3);
    }
}

// ---------------- launch ----------------
extern "C" void kernel_launch(void* const* d_in, const int* in_sizes, int n_in,
                              void* d_out, int out_size, void* d_ws, size_t ws_size,
                              hipStream_t stream) {
    const float* x     = (const float*)d_in[0];
    const float* inter = (const float*)d_in[1];
    const float* qkv_w = (const float*)d_in[2];
    const float* qkv_b = (const float*)d_in[3];
    const float* out_w = (const float*)d_in[4];
    const float* out_b = (const float*)d_in[5];
    const float* n1g   = (const float*)d_in[6];
    const float* n1b   = (const float*)d_in[7];
    const float* n2g   = (const float*)d_in[8];
    const float* n2b   = (const float*)d_in[9];
    const float* iw    = (const float*)d_in[10];
    const float* fw1   = (const float*)d_in[11];
    const float* fb1   = (const float*)d_in[12];
    const float* fw2   = (const float*)d_in[13];
    const float* fb2   = (const float*)d_in[14];
    float* out = (float*)d_out;

    // workspace layout (bytes): total 190,840,832
    //   qbuf    @ 0           : 16,777,216  (16384 x 512 bf16 Q)
    //   kfrag   @ 16777216    : 16,777,216  (fragment blobs)
    //   vfrag   @ 33554432    : 16,777,216  (fragment blobs)
    //   attnout @ 50331648    : 16,777,216
    //   x2      @ 67108864    : 33,554,432  (fp32)
    //   h_bf    @ 100663296   : 16,777,216
    //   ffnmid  @ 117440512   : 67,108,864
    //   weights @ 184549376   : ~6.3 MB
    if (ws_size < 190840832ull) return;
    char* ws = (char*)d_ws;
    unsigned short* qbuf    = (unsigned short*)(ws);
    unsigned short* kfrag   = (unsigned short*)(ws + 16777216ull);
    unsigned short* vfrag   = (unsigned short*)(ws + 33554432ull);
    unsigned short* attnout = (unsigned short*)(ws + 50331648ull);
    float*          x2      = (float*)(ws + 67108864ull);
    unsigned short* h_bf    = (unsigned short*)(ws + 100663296ull);
    unsigned short* ffnmid  = (unsigned short*)(ws + 117440512ull);
    unsigned short* qkv_wT  = (unsigned short*)(ws + 184549376ull);
    unsigned short* out_wT  = (unsigned short*)(ws + 186122240ull);
    unsigned short* fw1T    = (unsigned short*)(ws + 186646528ull);
    unsigned short* fw2T    = (unsigned short*)(ws + 188743680ull);

    const int M = BB * LL;  // 16384

    // 0. weight transposes -> bf16 B^T
    transpose_bf16<<<dim3(1536 / 32, 512 / 32), 256, 0, stream>>>(qkv_w, qkv_wT, 512, 1536);
    transpose_bf16<<<dim3(512 / 32, 512 / 32), 256, 0, stream>>>(out_w, out_wT, 512, 512);
    transpose_bf16<<<dim3(2048 / 32, 512 / 32), 256, 0, stream>>>(fw1, fw1T, 512, 2048);
    transpose_bf16<<<dim3(512 / 32, 2048 / 32), 256, 0, stream>>>(fw2, fw2T, 2048, 512);
    // 1. LN1: x -> h_bf
    ln_kernel<<<M, 256, 0, stream>>>(x, n1g, n1b, h_bf);
    // 2. qkv GEMM -> qbuf + kfrag + vfrag (fragment-packed K/V)
    gemm_mfma<0, 0, 2><<<dim3(1536 / 128, M / 128), 256, 0, stream>>>(
        h_bf, qkv_wT, qkv_b, nullptr, qbuf, kfrag, vfrag, M, 1536, 512);
    // 3. fused flash attention (per-head blocks, barrier-free)
    flash_kernel<<<dim3(NH, LL / 128, BB), 512, 0, stream>>>(qbuf, kfrag, vfrag, inter, iw, attnout);
    // 4. x2 = x + attnout @ out_w + out_b
    gemm_mfma<0, 1, 0><<<dim3(512 / 128, M / 128), 256, 0, stream>>>(
        attnout, out_wT, out_b, x, x2, nullptr, nullptr, M, 512, 512);
    // 5. LN2: x2 -> h_bf
    ln_kernel<<<M, 256, 0, stream>>>(x2, n2g, n2b, h_bf);
    // 6. ffnmid = gelu(h2 @ fw1 + fb1) -> bf16
    gemm_mfma<1, 0, 1><<<dim3(2048 / 128, M / 128), 256, 0, stream>>>(
        h_bf, fw1T, fb1, nullptr, ffnmid, nullptr, nullptr, M, 2048, 512);
    // 7. out = x2 + ffnmid @ fw2 + fb2
    gemm_mfma<0, 1, 0><<<dim3(512 / 128, M / 128), 256, 0, stream>>>(
        ffnmid, fw2T, fb2, x2, out, nullptr, nullptr, M, 512, 2048);
}

// Round 5
// 535.921 us; speedup vs baseline: 1.1867x; 1.1867x over previous
//
#include <hip/hip_runtime.h>
#include <math.h>

#define BB 32
#define LL 512
#define DD 512
#define NH 8
#define HD 64

typedef __attribute__((ext_vector_type(8))) short bf16x8;
typedef __attribute__((ext_vector_type(4))) float f32x4;

__device__ __forceinline__ unsigned short f2bf(float x) {
    union { float f; unsigned u; } v; v.f = x;
    unsigned r = v.u + 0x7fffu + ((v.u >> 16) & 1u);  // RNE
    return (unsigned short)(r >> 16);
}

// ---------------- reductions ----------------
__device__ __forceinline__ float warp_sum(float v) {
    #pragma unroll
    for (int o = 32; o > 0; o >>= 1) v += __shfl_down(v, o);
    return v;
}

// ---------------- LayerNorm: one block per row of 512, bf16 out ----------------
__global__ void ln_kernel(const float* __restrict__ X, const float* __restrict__ g,
                          const float* __restrict__ b, unsigned short* __restrict__ Y) {
    __shared__ float red[8];
    const size_t base = (size_t)blockIdx.x * DD;
    const int t = threadIdx.x;
    float x0 = X[base + t], x1 = X[base + t + 256];
    float s = warp_sum(x0 + x1);
    float q = warp_sum(x0 * x0 + x1 * x1);
    if ((t & 63) == 0) { red[t >> 6] = s; red[4 + (t >> 6)] = q; }
    __syncthreads();
    float S = red[0] + red[1] + red[2] + red[3];
    float Q = red[4] + red[5] + red[6] + red[7];
    float mu  = S * (1.0f / 512.0f);
    float var = Q * (1.0f / 512.0f) - mu * mu;
    float r = rsqrtf(var + 1e-5f);
    Y[base + t]       = f2bf((x0 - mu) * r * g[t] + b[t]);
    Y[base + t + 256] = f2bf((x1 - mu) * r * g[t + 256] + b[t + 256]);
}

// ---------------- weight transpose + bf16 cast: W (K x N) -> WT (N x K) ----------------
__global__ void transpose_bf16(const float* __restrict__ W, unsigned short* __restrict__ WT,
                               int K, int N) {
    __shared__ float t[32][33];
    const int n0 = blockIdx.x * 32, k0 = blockIdx.y * 32;
    const int tx = threadIdx.x & 31, ty = threadIdx.x >> 5;
    #pragma unroll
    for (int r = 0; r < 32; r += 8)
        t[ty + r][tx] = W[(size_t)(k0 + ty + r) * N + n0 + tx];
    __syncthreads();
    #pragma unroll
    for (int r = 0; r < 32; r += 8)
        WT[(size_t)(n0 + ty + r) * K + k0 + tx] = f2bf(t[tx][ty + r]);
}

// ---------------- bf16 MFMA GEMM ----------------
// A: M x K bf16 row-major; BT: N x K bf16 row-major. 128x128 tile, BK=64.
// Grid is 1D (nx*ny blocks, nx = N/128, bn-fast order) with an XCD-bijective
// chunked swizzle (T1): hardware round-robins blockIdx%8 across the 8 XCDs,
// so o = (bid&7)*chunk + bid>>3 gives each XCD a CONTIGUOUS run of the
// original order. Consecutive o share the same A-panel (bn-fast) -> the
// panel + the whole B weight matrix stay resident in that XCD's 4MB L2
// instead of being replicated into all 8. nwg % 8 == 0 for all launches
// (1536/512/2048/512) -> bijective (ERRATA #11 satisfied).
// OM: 0 = f32 out, 1 = bf16 out,
//     2 = qkv split: Q -> Cv row-major [row][512]; K -> kfrag blobs; V -> vfrag blobs.
// Fragment blob layout (1 KB each): idx [b][h][kt][kk][j], element (lane*8 + e)
//   K: lane=hi*16+lo holds K[kpos=kt*64+j*16+lo][d=kk*32+hi*8+e]
//   V: lane=hi*16+lo holds V[d=j*16+lo][kpos=kt*64+kk*32+hi*8+e]
template <int ACT, int RES, int OM>
__global__ __launch_bounds__(256)
void gemm_mfma(const unsigned short* __restrict__ A, const unsigned short* __restrict__ BT,
               const float* __restrict__ bias, const float* __restrict__ res,
               void* __restrict__ Cv, unsigned short* __restrict__ kfrag,
               unsigned short* __restrict__ vfrag, int M, int N, int K) {
    __shared__ unsigned short As[128 * 64];
    __shared__ unsigned short Bs[128 * 64];
    const int tid = threadIdx.x;
    const int wave = tid >> 6, lane = tid & 63;
    const int wm = (wave >> 1) * 64, wn = (wave & 1) * 64;

    // XCD-bijective chunked swizzle
    const int nx = N >> 7;
    const int chunk = (int)gridDim.x >> 3;
    const int o = ((int)blockIdx.x & 7) * chunk + ((int)blockIdx.x >> 3);
    const int bn = (o % nx) * 128;
    const int bm = (o / nx) * 128;

    f32x4 acc[4][4] = {};

    for (int k0 = 0; k0 < K; k0 += 64) {
        __syncthreads();
        #pragma unroll
        for (int it = 0; it < 4; ++it) {
            const int s = it * 256 + tid;
            const int row = s >> 3, pch = s & 7;
            const int lch = pch ^ (row & 7);
            const unsigned short* ga = A + (size_t)(bm + row) * K + k0 + lch * 8;
            __builtin_amdgcn_global_load_lds(
                (const __attribute__((address_space(1))) void*)ga,
                (__attribute__((address_space(3))) void*)(As + s * 8), 16, 0, 0);
            const unsigned short* gb = BT + (size_t)(bn + row) * K + k0 + lch * 8;
            __builtin_amdgcn_global_load_lds(
                (const __attribute__((address_space(1))) void*)gb,
                (__attribute__((address_space(3))) void*)(Bs + s * 8), 16, 0, 0);
        }
        __syncthreads();
        #pragma unroll
        for (int ks = 0; ks < 2; ++ks) {
            bf16x8 af[4], bfr[4];
            #pragma unroll
            for (int i = 0; i < 4; ++i) {
                const int row = wm + i * 16 + (lane & 15);
                const int pch = (ks * 4 + (lane >> 4)) ^ (row & 7);
                af[i] = *(const bf16x8*)(As + row * 64 + pch * 8);
            }
            #pragma unroll
            for (int j = 0; j < 4; ++j) {
                const int row = wn + j * 16 + (lane & 15);
                const int pch = (ks * 4 + (lane >> 4)) ^ (row & 7);
                bfr[j] = *(const bf16x8*)(Bs + row * 64 + pch * 8);
            }
            #pragma unroll
            for (int i = 0; i < 4; ++i)
                #pragma unroll
                for (int j = 0; j < 4; ++j)
                    acc[i][j] = __builtin_amdgcn_mfma_f32_16x16x32_bf16(
                        af[i], bfr[j], acc[i][j], 0, 0, 0);
        }
    }

    const int cl = lane & 15, rq = (lane >> 4) * 4;
    #pragma unroll
    for (int j = 0; j < 4; ++j) {
        const int col = bn + wn + j * 16 + cl;
        const float bv = bias[col];
        #pragma unroll
        for (int i = 0; i < 4; ++i) {
            const int r0 = bm + wm + i * 16 + rq;
            #pragma unroll
            for (int r = 0; r < 4; ++r) {
                float v = acc[i][j][r] + bv;
                if (ACT == 1) v = 0.5f * v * (1.0f + erff(v * 0.70710678118654752f));
                if (RES) v += res[(size_t)(r0 + r) * N + col];
                if (OM == 0) {
                    ((float*)Cv)[(size_t)(r0 + r) * N + col] = v;
                } else if (OM == 1) {
                    ((unsigned short*)Cv)[(size_t)(r0 + r) * N + col] = f2bf(v);
                } else {
                    const int row = r0 + r;
                    const int b = row >> 9, kpos = row & 511;
                    if (col < 512) {
                        ((unsigned short*)Cv)[(size_t)row * 512 + col] = f2bf(v);
                    } else if (col < 1024) {
                        const int h = (col - 512) >> 6, dd = (col - 512) & 63;
                        const int kt = kpos >> 6, jj = (kpos >> 4) & 3, lo2 = kpos & 15;
                        const int kk = dd >> 5, hi2 = (dd >> 3) & 3, e = dd & 7;
                        kfrag[((((size_t)(b * NH + h) * 8 + kt) * 2 + kk) * 4 + jj) * 512
                              + (hi2 * 16 + lo2) * 8 + e] = f2bf(v);
                    } else {
                        const int h = (col - 1024) >> 6, dd = (col - 1024) & 63;
                        const int kt = kpos >> 6, kk = (kpos >> 5) & 1, hi2 = (kpos >> 3) & 3, e = kpos & 7;
                        const int jj = dd >> 4, lo2 = dd & 15;
                        vfrag[((((size_t)(b * NH + h) * 8 + kt) * 2 + kk) * 4 + jj) * 512
                              + (hi2 * 16 + lo2) * 8 + e] = f2bf(v);
                    }
                }
            }
        }
    }
}

// ---------------- fused flash attention v4 (reverted keeper) ----------------
// grid: (qg=32, b=32), 512 threads = 8 waves; wave w = head w.
// v4 = global_load_lds inter staging (exactly-once HBM: the inter element
// feeds ALL 8 heads, so heads must be co-located in the block) + swapped
// QK^T compute core. v5's per-head-block split re-amplified HBM 2.8x and
// ran 190us -> reverted. Known counters: ~102us, FETCH ~208MB, 5.77M
// bank conflicts, occupancy 38%.
__global__ __launch_bounds__(512)
void flash_kernel(const unsigned short* __restrict__ qbuf,
                  const unsigned short* __restrict__ kfrag,
                  const unsigned short* __restrict__ vfrag,
                  const float* __restrict__ inter,
                  const float* __restrict__ iw,
                  unsigned short* __restrict__ O) {
    __shared__ float it[2][16 * 256];               // 2 x 16 KB inter tiles (linear)
    __shared__ unsigned short plds[8][16 * 72];     // per-wave P tile
    const int qg = blockIdx.x, b = blockIdx.y;
    const int tid = threadIdx.x, wave = tid >> 6, lane = tid & 63;
    const int h = wave;
    const int lo = lane & 15, hi = lane >> 4;

    const float iw0 = iw[h], iw1 = iw[8 + h], iw2 = iw[16 + h], iw3 = iw[24 + h];
    const float* interb = inter + (size_t)b * 512 * 512 * 4;
    unsigned short* pw = &plds[wave][0];

    // Q fragment (fixed for whole block): q-row = lo, d = kk*32 + hi*8 + e
    const unsigned short* qp = qbuf + ((size_t)(b * 512 + qg * 16 + lo)) * 512 + h * 64 + hi * 8;
    const bf16x8 qf0 = *(const bf16x8*)(qp);
    const bf16x8 qf1 = *(const bf16x8*)(qp + 32);

    // fragment blob bases (kt stride = 2*4*512 u16 = 4096)
    const unsigned short* kfb = kfrag + (size_t)(b * NH + h) * 32768 + (size_t)lane * 8;
    const unsigned short* vfb = vfrag + (size_t)(b * NH + h) * 32768 + (size_t)lane * 8;

    // staging: wave w stages tile rows {2w, 2w+1}; LDS dest linear
    // (uniform row base + lane*16B); global source chunk = lane ^ (row&7).
    const int srow0 = wave * 2, srow1 = wave * 2 + 1;
    const float* sg0 = interb + (((size_t)(qg * 16 + srow0)) * 512 + (lane ^ (srow0 & 7))) * 4;
    const float* sg1 = interb + (((size_t)(qg * 16 + srow1)) * 512 + (lane ^ (srow1 & 7))) * 4;

    f32x4 o[4] = {};
    float m = -1e30f, lsum = 0.0f;

    // prologue: stage tile 0 into it[0]
    __builtin_amdgcn_global_load_lds(
        (const __attribute__((address_space(1))) void*)sg0,
        (__attribute__((address_space(3))) void*)(&it[0][srow0 * 256] + lane * 4), 16, 0, 0);
    __builtin_amdgcn_global_load_lds(
        (const __attribute__((address_space(1))) void*)sg1,
        (__attribute__((address_space(3))) void*)(&it[0][srow1 * 256] + lane * 4), 16, 0, 0);

    #pragma unroll 1
    for (int kt = 0; kt < 8; ++kt) {
        const int buf = kt & 1;
        __syncthreads();  // it[buf] staged & visible; it[buf^1] free to overwrite
        // (1) K fragments (oldest in vmcnt queue -> counted wait at QK^T)
        const unsigned short* kp = kfb + kt * 4096;
        bf16x8 kf[8];
        #pragma unroll
        for (int jj = 0; jj < 8; ++jj)
            kf[jj] = *(const bf16x8*)(kp + jj * 512);
        // (2) V fragments (consumed at PV; older than stage so PV's wait
        //     never forces the HBM stage to complete)
        const unsigned short* vp = vfb + kt * 4096;
        bf16x8 vf[8];
        #pragma unroll
        for (int jj = 0; jj < 8; ++jj)
            vf[jj] = *(const bf16x8*)(vp + jj * 512);
        // (3) stage tile kt+1 (youngest; drains at next barrier)
        if (kt < 7) {
            const int kb2 = (kt + 1) * 64;
            __builtin_amdgcn_global_load_lds(
                (const __attribute__((address_space(1))) void*)(sg0 + kb2 * 4),
                (__attribute__((address_space(3))) void*)(&it[buf ^ 1][srow0 * 256] + lane * 4),
                16, 0, 0);
            __builtin_amdgcn_global_load_lds(
                (const __attribute__((address_space(1))) void*)(sg1 + kb2 * 4),
                (__attribute__((address_space(3))) void*)(&it[buf ^ 1][srow1 * 256] + lane * 4),
                16, 0, 0);
        }
        __builtin_amdgcn_sched_barrier(0);
        // (4) S^T = K Q^T : lane owns q = lo, k = j*16 + hi*4 + r
        f32x4 s4[4] = {};
        __builtin_amdgcn_s_setprio(1);
        #pragma unroll
        for (int j = 0; j < 4; ++j)
            s4[j] = __builtin_amdgcn_mfma_f32_16x16x32_bf16(kf[j], qf0, s4[j], 0, 0, 0);
        #pragma unroll
        for (int j = 0; j < 4; ++j)
            s4[j] = __builtin_amdgcn_mfma_f32_16x16x32_bf16(kf[4 + j], qf1, s4[j], 0, 0, 0);
        __builtin_amdgcn_s_setprio(0);
        // (5) bias + scale from LDS (swizzled read: chunk c stored at c^(lo&7))
        {
            const float* bb = &it[buf][lo * 256];
            const int x7 = lo & 7;
            #pragma unroll
            for (int j = 0; j < 4; ++j) {
                #pragma unroll
                for (int r = 0; r < 4; ++r) {
                    const int c = (((hi * 4 + r) ^ x7) + j * 16) * 4;
                    const float4 f = *(const float4*)(bb + c);
                    s4[j][r] = s4[j][r] * 0.125f + f.x * iw0 + f.y * iw1 + f.z * iw2 + f.w * iw3;
                }
            }
        }
        // (6) online softmax, per-lane row q = lo (replicated over hi groups)
        float t0 = fmaxf(fmaxf(s4[0][0], s4[0][1]), fmaxf(s4[0][2], s4[0][3]));
        float t1 = fmaxf(fmaxf(s4[1][0], s4[1][1]), fmaxf(s4[1][2], s4[1][3]));
        float t2 = fmaxf(fmaxf(s4[2][0], s4[2][1]), fmaxf(s4[2][2], s4[2][3]));
        float t3 = fmaxf(fmaxf(s4[3][0], s4[3][1]), fmaxf(s4[3][2], s4[3][3]));
        float mx = fmaxf(fmaxf(t0, t1), fmaxf(t2, t3));
        mx = fmaxf(mx, __shfl_xor(mx, 16));
        mx = fmaxf(mx, __shfl_xor(mx, 32));
        const float mn = fmaxf(m, mx);
        const float al = __expf(m - mn);
        m = mn;
        #pragma unroll
        for (int j = 0; j < 4; ++j)
            #pragma unroll
            for (int r = 0; r < 4; ++r)
                s4[j][r] = __expf(s4[j][r] - mn);
        float u0 = (s4[0][0] + s4[0][1]) + (s4[0][2] + s4[0][3]);
        float u1 = (s4[1][0] + s4[1][1]) + (s4[1][2] + s4[1][3]);
        float u2 = (s4[2][0] + s4[2][1]) + (s4[2][2] + s4[2][3]);
        float u3 = (s4[3][0] + s4[3][1]) + (s4[3][2] + s4[3][3]);
        float ts = (u0 + u1) + (u2 + u3);
        ts += __shfl_xor(ts, 16);
        ts += __shfl_xor(ts, 32);
        lsum = lsum * al + ts;
        // (7) redistribute alpha to C-layout rows (q = hi*4 + r)
        const float aR0 = __shfl(al, hi * 4 + 0);
        const float aR1 = __shfl(al, hi * 4 + 1);
        const float aR2 = __shfl(al, hi * 4 + 2);
        const float aR3 = __shfl(al, hi * 4 + 3);
        #pragma unroll
        for (int j2 = 0; j2 < 4; ++j2) {
            o[j2][0] *= aR0; o[j2][1] *= aR1; o[j2][2] *= aR2; o[j2][3] *= aR3;
        }
        // (8) P -> LDS, packed b64, wave-private (no barrier needed)
        uint2* pq = (uint2*)(pw + lo * 72);
        #pragma unroll
        for (int j = 0; j < 4; ++j) {
            uint2 d;
            d.x = (unsigned)f2bf(s4[j][0]) | ((unsigned)f2bf(s4[j][1]) << 16);
            d.y = (unsigned)f2bf(s4[j][2]) | ((unsigned)f2bf(s4[j][3]) << 16);
            pq[j * 4 + hi] = d;
        }
        // (9) O += P V
        __builtin_amdgcn_s_setprio(1);
        #pragma unroll
        for (int kk = 0; kk < 2; ++kk) {
            const bf16x8 pf = *(const bf16x8*)(pw + lo * 72 + kk * 32 + hi * 8);
            #pragma unroll
            for (int j2 = 0; j2 < 4; ++j2)
                o[j2] = __builtin_amdgcn_mfma_f32_16x16x32_bf16(
                    pf, vf[kk * 4 + j2], o[j2], 0, 0, 0);
        }
        __builtin_amdgcn_s_setprio(0);
    }

    // ---- epilogue ----
    const float iR0 = 1.0f / __shfl(lsum, hi * 4 + 0);
    const float iR1 = 1.0f / __shfl(lsum, hi * 4 + 1);
    const float iR2 = 1.0f / __shfl(lsum, hi * 4 + 2);
    const float iR3 = 1.0f / __shfl(lsum, hi * 4 + 3);
    const int qC0 = qg * 16 + hi * 4;
    #pragma unroll
    for (int j2 = 0; j2 < 4; ++j2) {
        O[(size_t)(b * 512 + qC0 + 0) * 512 + h * 64 + j2 * 16 + lo] = f2bf(o[j2][0] * iR0);
        O[(size_t)(b * 512 + qC0 + 1) * 512 + h * 64 + j2 * 16 + lo] = f2bf(o[j2][1] * iR1);
        O[(size_t)(b * 512 + qC0 + 2) * 512 + h * 64 + j2 * 16 + lo] = f2bf(o[j2][2] * iR2);
        O[(size_t)(b * 512 + qC0 + 3) * 512 + h * 64 + j2 * 16 + lo] = f2bf(o[j2][3] * iR3);
    }
}

// ---------------- launch ----------------
extern "C" void kernel_launch(void* const* d_in, const int* in_sizes, int n_in,
                              void* d_out, int out_size, void* d_ws, size_t ws_size,
                              hipStream_t stream) {
    const float* x     = (const float*)d_in[0];
    const float* inter = (const float*)d_in[1];
    const float* qkv_w = (const float*)d_in[2];
    const float* qkv_b = (const float*)d_in[3];
    const float* out_w = (const float*)d_in[4];
    const float* out_b = (const float*)d_in[5];
    const float* n1g   = (const float*)d_in[6];
    const float* n1b   = (const float*)d_in[7];
    const float* n2g   = (const float*)d_in[8];
    const float* n2b   = (const float*)d_in[9];
    const float* iw    = (const float*)d_in[10];
    const float* fw1   = (const float*)d_in[11];
    const float* fb1   = (const float*)d_in[12];
    const float* fw2   = (const float*)d_in[13];
    const float* fb2   = (const float*)d_in[14];
    float* out = (float*)d_out;

    // workspace layout (bytes): total 190,840,832
    //   qbuf    @ 0           : 16,777,216  (16384 x 512 bf16 Q)
    //   kfrag   @ 16777216    : 16,777,216  (fragment blobs)
    //   vfrag   @ 33554432    : 16,777,216  (fragment blobs)
    //   attnout @ 50331648    : 16,777,216
    //   x2      @ 67108864    : 33,554,432  (fp32)
    //   h_bf    @ 100663296   : 16,777,216
    //   ffnmid  @ 117440512   : 67,108,864
    //   weights @ 184549376   : ~6.3 MB
    if (ws_size < 190840832ull) return;
    char* ws = (char*)d_ws;
    unsigned short* qbuf    = (unsigned short*)(ws);
    unsigned short* kfrag   = (unsigned short*)(ws + 16777216ull);
    unsigned short* vfrag   = (unsigned short*)(ws + 33554432ull);
    unsigned short* attnout = (unsigned short*)(ws + 50331648ull);
    float*          x2      = (float*)(ws + 67108864ull);
    unsigned short* h_bf    = (unsigned short*)(ws + 100663296ull);
    unsigned short* ffnmid  = (unsigned short*)(ws + 117440512ull);
    unsigned short* qkv_wT  = (unsigned short*)(ws + 184549376ull);
    unsigned short* out_wT  = (unsigned short*)(ws + 186122240ull);
    unsigned short* fw1T    = (unsigned short*)(ws + 186646528ull);
    unsigned short* fw2T    = (unsigned short*)(ws + 188743680ull);

    const int M = BB * LL;  // 16384

    // 0. weight transposes -> bf16 B^T
    transpose_bf16<<<dim3(1536 / 32, 512 / 32), 256, 0, stream>>>(qkv_w, qkv_wT, 512, 1536);
    transpose_bf16<<<dim3(512 / 32, 512 / 32), 256, 0, stream>>>(out_w, out_wT, 512, 512);
    transpose_bf16<<<dim3(2048 / 32, 512 / 32), 256, 0, stream>>>(fw1, fw1T, 512, 2048);
    transpose_bf16<<<dim3(512 / 32, 2048 / 32), 256, 0, stream>>>(fw2, fw2T, 2048, 512);
    // 1. LN1: x -> h_bf
    ln_kernel<<<M, 256, 0, stream>>>(x, n1g, n1b, h_bf);
    // 2. qkv GEMM -> qbuf + kfrag + vfrag (fragment-packed K/V); 1D swizzled grid
    gemm_mfma<0, 0, 2><<<dim3((1536 / 128) * (M / 128)), 256, 0, stream>>>(
        h_bf, qkv_wT, qkv_b, nullptr, qbuf, kfrag, vfrag, M, 1536, 512);
    // 3. fused flash attention (v4 keeper)
    flash_kernel<<<dim3(LL / 16, BB), 512, 0, stream>>>(qbuf, kfrag, vfrag, inter, iw, attnout);
    // 4. x2 = x + attnout @ out_w + out_b
    gemm_mfma<0, 1, 0><<<dim3((512 / 128) * (M / 128)), 256, 0, stream>>>(
        attnout, out_wT, out_b, x, x2, nullptr, nullptr, M, 512, 512);
    // 5. LN2: x2 -> h_bf
    ln_kernel<<<M, 256, 0, stream>>>(x2, n2g, n2b, h_bf);
    // 6. ffnmid = gelu(h2 @ fw1 + fb1) -> bf16
    gemm_mfma<1, 0, 1><<<dim3((2048 / 128) * (M / 128)), 256, 0, stream>>>(
        h_bf, fw1T, fb1, nullptr, ffnmid, nullptr, nullptr, M, 2048, 512);
    // 7. out = x2 + ffnmid @ fw2 + fb2
    gemm_mfma<0, 1, 0><<<dim3((512 / 128) * (M / 128)), 256, 0, stream>>>(
        ffnmid, fw2T, fb2, x2, out, nullptr, nullptr, M, 512, 2048);
}

// Round 6
// 500.642 us; speedup vs baseline: 1.2703x; 1.0705x over previous
//
#include <hip/hip_runtime.h>
#include <math.h>

#define BB 32
#define LL 512
#define DD 512
#define NH 8
#define HD 64

typedef __attribute__((ext_vector_type(8))) short bf16x8;
typedef __attribute__((ext_vector_type(4))) float f32x4;

__device__ __forceinline__ unsigned short f2bf(float x) {
    union { float f; unsigned u; } v; v.f = x;
    unsigned r = v.u + 0x7fffu + ((v.u >> 16) & 1u);  // RNE
    return (unsigned short)(r >> 16);
}

// ---------------- reductions ----------------
__device__ __forceinline__ float warp_sum(float v) {
    #pragma unroll
    for (int o = 32; o > 0; o >>= 1) v += __shfl_down(v, o);
    return v;
}

// ---------------- LayerNorm: one block per row of 512, bf16 out ----------------
__global__ void ln_kernel(const float* __restrict__ X, const float* __restrict__ g,
                          const float* __restrict__ b, unsigned short* __restrict__ Y) {
    __shared__ float red[8];
    const size_t base = (size_t)blockIdx.x * DD;
    const int t = threadIdx.x;
    float x0 = X[base + t], x1 = X[base + t + 256];
    float s = warp_sum(x0 + x1);
    float q = warp_sum(x0 * x0 + x1 * x1);
    if ((t & 63) == 0) { red[t >> 6] = s; red[4 + (t >> 6)] = q; }
    __syncthreads();
    float S = red[0] + red[1] + red[2] + red[3];
    float Q = red[4] + red[5] + red[6] + red[7];
    float mu  = S * (1.0f / 512.0f);
    float var = Q * (1.0f / 512.0f) - mu * mu;
    float r = rsqrtf(var + 1e-5f);
    Y[base + t]       = f2bf((x0 - mu) * r * g[t] + b[t]);
    Y[base + t + 256] = f2bf((x1 - mu) * r * g[t + 256] + b[t + 256]);
}

// ---------------- weight transpose + bf16 cast: W (K x N) -> WT (N x K) ----------------
__global__ void transpose_bf16(const float* __restrict__ W, unsigned short* __restrict__ WT,
                               int K, int N) {
    __shared__ float t[32][33];
    const int n0 = blockIdx.x * 32, k0 = blockIdx.y * 32;
    const int tx = threadIdx.x & 31, ty = threadIdx.x >> 5;
    #pragma unroll
    for (int r = 0; r < 32; r += 8)
        t[ty + r][tx] = W[(size_t)(k0 + ty + r) * N + n0 + tx];
    __syncthreads();
    #pragma unroll
    for (int r = 0; r < 32; r += 8)
        WT[(size_t)(n0 + ty + r) * K + k0 + tx] = f2bf(t[tx][ty + r]);
}

// ---------------- bf16 MFMA GEMM, 2-phase double-buffered staging ----------------
// A: M x K bf16 row-major; BT: N x K bf16 row-major. 128x128 tile, BK=64.
// v6: T3-minimal 2-phase. Two STATIC LDS buffer pairs (no runtime-indexed
// LDS -> alias-clean), loop unrolled by 2. Per K-step ONE barrier; stage of
// tile t+1 is issued BEFORE compute(t) and drains at the NEXT barrier -> HBM/
// L2 latency hides under ~16 MFMA + 8 ds_read. Requires K/64 even (8 or 32
// here). LDS 64 KB -> 2 blocks/CU (trades TLP for in-block overlap; at
// K=512 the serial stage-drain was ~2/3 of block life).
// Grid 1D with XCD-bijective chunked swizzle (T1, kept from R5).
// OM: 0 = f32 out, 1 = bf16 out,
//     2 = qkv split: Q -> Cv row-major [row][512]; K -> kfrag blobs; V -> vfrag blobs.
template <int ACT, int RES, int OM>
__global__ __launch_bounds__(256)
void gemm_mfma(const unsigned short* __restrict__ A, const unsigned short* __restrict__ BT,
               const float* __restrict__ bias, const float* __restrict__ res,
               void* __restrict__ Cv, unsigned short* __restrict__ kfrag,
               unsigned short* __restrict__ vfrag, int M, int N, int K) {
    __shared__ unsigned short As0[128 * 64];
    __shared__ unsigned short Bs0[128 * 64];
    __shared__ unsigned short As1[128 * 64];
    __shared__ unsigned short Bs1[128 * 64];
    const int tid = threadIdx.x;
    const int wave = tid >> 6, lane = tid & 63;
    const int wm = (wave >> 1) * 64, wn = (wave & 1) * 64;

    // XCD-bijective chunked swizzle
    const int nx = N >> 7;
    const int chunk = (int)gridDim.x >> 3;
    const int o = ((int)blockIdx.x & 7) * chunk + ((int)blockIdx.x >> 3);
    const int bn = (o % nx) * 128;
    const int bm = (o / nx) * 128;

    f32x4 acc[4][4] = {};

    // staging: 4 x 2 gll of 16B per thread; XOR-swizzled source chunk,
    // linear LDS dest (gll requirement).
    auto stage = [&](unsigned short* AS, unsigned short* BS, int k0) {
        #pragma unroll
        for (int it = 0; it < 4; ++it) {
            const int s = it * 256 + tid;
            const int row = s >> 3, pch = s & 7;
            const int lch = pch ^ (row & 7);
            const unsigned short* ga = A + (size_t)(bm + row) * K + k0 + lch * 8;
            __builtin_amdgcn_global_load_lds(
                (const __attribute__((address_space(1))) void*)ga,
                (__attribute__((address_space(3))) void*)(AS + s * 8), 16, 0, 0);
            const unsigned short* gb = BT + (size_t)(bn + row) * K + k0 + lch * 8;
            __builtin_amdgcn_global_load_lds(
                (const __attribute__((address_space(1))) void*)gb,
                (__attribute__((address_space(3))) void*)(BS + s * 8), 16, 0, 0);
        }
    };

    auto compute = [&](const unsigned short* AS, const unsigned short* BS) {
        #pragma unroll
        for (int ks = 0; ks < 2; ++ks) {
            bf16x8 af[4], bfr[4];
            #pragma unroll
            for (int i = 0; i < 4; ++i) {
                const int row = wm + i * 16 + (lane & 15);
                const int pch = (ks * 4 + (lane >> 4)) ^ (row & 7);
                af[i] = *(const bf16x8*)(AS + row * 64 + pch * 8);
            }
            #pragma unroll
            for (int j = 0; j < 4; ++j) {
                const int row = wn + j * 16 + (lane & 15);
                const int pch = (ks * 4 + (lane >> 4)) ^ (row & 7);
                bfr[j] = *(const bf16x8*)(BS + row * 64 + pch * 8);
            }
            #pragma unroll
            for (int i = 0; i < 4; ++i)
                #pragma unroll
                for (int j = 0; j < 4; ++j)
                    acc[i][j] = __builtin_amdgcn_mfma_f32_16x16x32_bf16(
                        af[i], bfr[j], acc[i][j], 0, 0, 0);
        }
    };

    // prologue: stage tile 0 into buffer pair 0
    stage(As0, Bs0, 0);
    // main loop: 2 K-steps per iteration, one barrier per K-step.
    for (int k0 = 0; k0 < K; k0 += 128) {
        __syncthreads();                         // drains stage of As0/Bs0
        if (k0 + 64 < K) stage(As1, Bs1, k0 + 64);   // flies under compute
        compute(As0, Bs0);
        __syncthreads();                         // drains stage of As1/Bs1
        if (k0 + 128 < K) stage(As0, Bs0, k0 + 128);
        compute(As1, Bs1);
    }

    const int cl = lane & 15, rq = (lane >> 4) * 4;
    #pragma unroll
    for (int j = 0; j < 4; ++j) {
        const int col = bn + wn + j * 16 + cl;
        const float bv = bias[col];
        #pragma unroll
        for (int i = 0; i < 4; ++i) {
            const int r0 = bm + wm + i * 16 + rq;
            #pragma unroll
            for (int r = 0; r < 4; ++r) {
                float v = acc[i][j][r] + bv;
                if (ACT == 1) v = 0.5f * v * (1.0f + erff(v * 0.70710678118654752f));
                if (RES) v += res[(size_t)(r0 + r) * N + col];
                if (OM == 0) {
                    ((float*)Cv)[(size_t)(r0 + r) * N + col] = v;
                } else if (OM == 1) {
                    ((unsigned short*)Cv)[(size_t)(r0 + r) * N + col] = f2bf(v);
                } else {
                    const int row = r0 + r;
                    const int b = row >> 9, kpos = row & 511;
                    if (col < 512) {
                        ((unsigned short*)Cv)[(size_t)row * 512 + col] = f2bf(v);
                    } else if (col < 1024) {
                        const int h = (col - 512) >> 6, dd = (col - 512) & 63;
                        const int kt = kpos >> 6, jj = (kpos >> 4) & 3, lo2 = kpos & 15;
                        const int kk = dd >> 5, hi2 = (dd >> 3) & 3, e = dd & 7;
                        kfrag[((((size_t)(b * NH + h) * 8 + kt) * 2 + kk) * 4 + jj) * 512
                              + (hi2 * 16 + lo2) * 8 + e] = f2bf(v);
                    } else {
                        const int h = (col - 1024) >> 6, dd = (col - 1024) & 63;
                        const int kt = kpos >> 6, kk = (kpos >> 5) & 1, hi2 = (kpos >> 3) & 3, e = kpos & 7;
                        const int jj = dd >> 4, lo2 = dd & 15;
                        vfrag[((((size_t)(b * NH + h) * 8 + kt) * 2 + kk) * 4 + jj) * 512
                              + (hi2 * 16 + lo2) * 8 + e] = f2bf(v);
                    }
                }
            }
        }
    }
}

// ---------------- fused flash attention v4 + plds stride fix ----------------
// grid: (qg=32, b=32), 512 threads = 8 waves; wave w = head w.
// v6 change: plds row stride 72 -> 80 u16 (160 B, 16B-aligned). Old stride:
// PV's ds_read_b128 of P hit bank group 4*(lo+hi) mod 32 -> 8-way conflict
// (the stable 5.77M SQ_LDS_BANK_CONFLICT). Stride 80: read ~2-way (free),
// write ~4-way (was ~8). Everything else = v4 keeper.
__global__ __launch_bounds__(512)
void flash_kernel(const unsigned short* __restrict__ qbuf,
                  const unsigned short* __restrict__ kfrag,
                  const unsigned short* __restrict__ vfrag,
                  const float* __restrict__ inter,
                  const float* __restrict__ iw,
                  unsigned short* __restrict__ O) {
    __shared__ float it[2][16 * 256];               // 2 x 16 KB inter tiles (linear)
    __shared__ unsigned short plds[8][16 * 80];     // per-wave P tile, stride 80
    const int qg = blockIdx.x, b = blockIdx.y;
    const int tid = threadIdx.x, wave = tid >> 6, lane = tid & 63;
    const int h = wave;
    const int lo = lane & 15, hi = lane >> 4;

    const float iw0 = iw[h], iw1 = iw[8 + h], iw2 = iw[16 + h], iw3 = iw[24 + h];
    const float* interb = inter + (size_t)b * 512 * 512 * 4;
    unsigned short* pw = &plds[wave][0];

    // Q fragment (fixed for whole block): q-row = lo, d = kk*32 + hi*8 + e
    const unsigned short* qp = qbuf + ((size_t)(b * 512 + qg * 16 + lo)) * 512 + h * 64 + hi * 8;
    const bf16x8 qf0 = *(const bf16x8*)(qp);
    const bf16x8 qf1 = *(const bf16x8*)(qp + 32);

    // fragment blob bases (kt stride = 2*4*512 u16 = 4096)
    const unsigned short* kfb = kfrag + (size_t)(b * NH + h) * 32768 + (size_t)lane * 8;
    const unsigned short* vfb = vfrag + (size_t)(b * NH + h) * 32768 + (size_t)lane * 8;

    // staging: wave w stages tile rows {2w, 2w+1}; LDS dest linear
    // (uniform row base + lane*16B); global source chunk = lane ^ (row&7).
    const int srow0 = wave * 2, srow1 = wave * 2 + 1;
    const float* sg0 = interb + (((size_t)(qg * 16 + srow0)) * 512 + (lane ^ (srow0 & 7))) * 4;
    const float* sg1 = interb + (((size_t)(qg * 16 + srow1)) * 512 + (lane ^ (srow1 & 7))) * 4;

    f32x4 o[4] = {};
    float m = -1e30f, lsum = 0.0f;

    // prologue: stage tile 0 into it[0]
    __builtin_amdgcn_global_load_lds(
        (const __attribute__((address_space(1))) void*)sg0,
        (__attribute__((address_space(3))) void*)(&it[0][srow0 * 256] + lane * 4), 16, 0, 0);
    __builtin_amdgcn_global_load_lds(
        (const __attribute__((address_space(1))) void*)sg1,
        (__attribute__((address_space(3))) void*)(&it[0][srow1 * 256] + lane * 4), 16, 0, 0);

    #pragma unroll 1
    for (int kt = 0; kt < 8; ++kt) {
        const int buf = kt & 1;
        __syncthreads();  // it[buf] staged & visible; it[buf^1] free to overwrite
        // (1) K fragments (oldest in vmcnt queue -> counted wait at QK^T)
        const unsigned short* kp = kfb + kt * 4096;
        bf16x8 kf[8];
        #pragma unroll
        for (int jj = 0; jj < 8; ++jj)
            kf[jj] = *(const bf16x8*)(kp + jj * 512);
        // (2) V fragments (consumed at PV; older than stage so PV's wait
        //     never forces the HBM stage to complete)
        const unsigned short* vp = vfb + kt * 4096;
        bf16x8 vf[8];
        #pragma unroll
        for (int jj = 0; jj < 8; ++jj)
            vf[jj] = *(const bf16x8*)(vp + jj * 512);
        // (3) stage tile kt+1 (youngest; drains at next barrier)
        if (kt < 7) {
            const int kb2 = (kt + 1) * 64;
            __builtin_amdgcn_global_load_lds(
                (const __attribute__((address_space(1))) void*)(sg0 + kb2 * 4),
                (__attribute__((address_space(3))) void*)(&it[buf ^ 1][srow0 * 256] + lane * 4),
                16, 0, 0);
            __builtin_amdgcn_global_load_lds(
                (const __attribute__((address_space(1))) void*)(sg1 + kb2 * 4),
                (__attribute__((address_space(3))) void*)(&it[buf ^ 1][srow1 * 256] + lane * 4),
                16, 0, 0);
        }
        __builtin_amdgcn_sched_barrier(0);
        // (4) S^T = K Q^T : lane owns q = lo, k = j*16 + hi*4 + r
        f32x4 s4[4] = {};
        __builtin_amdgcn_s_setprio(1);
        #pragma unroll
        for (int j = 0; j < 4; ++j)
            s4[j] = __builtin_amdgcn_mfma_f32_16x16x32_bf16(kf[j], qf0, s4[j], 0, 0, 0);
        #pragma unroll
        for (int j = 0; j < 4; ++j)
            s4[j] = __builtin_amdgcn_mfma_f32_16x16x32_bf16(kf[4 + j], qf1, s4[j], 0, 0, 0);
        __builtin_amdgcn_s_setprio(0);
        // (5) bias + scale from LDS (swizzled read: chunk c stored at c^(lo&7))
        {
            const float* bb = &it[buf][lo * 256];
            const int x7 = lo & 7;
            #pragma unroll
            for (int j = 0; j < 4; ++j) {
                #pragma unroll
                for (int r = 0; r < 4; ++r) {
                    const int c = (((hi * 4 + r) ^ x7) + j * 16) * 4;
                    const float4 f = *(const float4*)(bb + c);
                    s4[j][r] = s4[j][r] * 0.125f + f.x * iw0 + f.y * iw1 + f.z * iw2 + f.w * iw3;
                }
            }
        }
        // (6) online softmax, per-lane row q = lo (replicated over hi groups)
        float t0 = fmaxf(fmaxf(s4[0][0], s4[0][1]), fmaxf(s4[0][2], s4[0][3]));
        float t1 = fmaxf(fmaxf(s4[1][0], s4[1][1]), fmaxf(s4[1][2], s4[1][3]));
        float t2 = fmaxf(fmaxf(s4[2][0], s4[2][1]), fmaxf(s4[2][2], s4[2][3]));
        float t3 = fmaxf(fmaxf(s4[3][0], s4[3][1]), fmaxf(s4[3][2], s4[3][3]));
        float mx = fmaxf(fmaxf(t0, t1), fmaxf(t2, t3));
        mx = fmaxf(mx, __shfl_xor(mx, 16));
        mx = fmaxf(mx, __shfl_xor(mx, 32));
        const float mn = fmaxf(m, mx);
        const float al = __expf(m - mn);
        m = mn;
        #pragma unroll
        for (int j = 0; j < 4; ++j)
            #pragma unroll
            for (int r = 0; r < 4; ++r)
                s4[j][r] = __expf(s4[j][r] - mn);
        float u0 = (s4[0][0] + s4[0][1]) + (s4[0][2] + s4[0][3]);
        float u1 = (s4[1][0] + s4[1][1]) + (s4[1][2] + s4[1][3]);
        float u2 = (s4[2][0] + s4[2][1]) + (s4[2][2] + s4[2][3]);
        float u3 = (s4[3][0] + s4[3][1]) + (s4[3][2] + s4[3][3]);
        float ts = (u0 + u1) + (u2 + u3);
        ts += __shfl_xor(ts, 16);
        ts += __shfl_xor(ts, 32);
        lsum = lsum * al + ts;
        // (7) redistribute alpha to C-layout rows (q = hi*4 + r)
        const float aR0 = __shfl(al, hi * 4 + 0);
        const float aR1 = __shfl(al, hi * 4 + 1);
        const float aR2 = __shfl(al, hi * 4 + 2);
        const float aR3 = __shfl(al, hi * 4 + 3);
        #pragma unroll
        for (int j2 = 0; j2 < 4; ++j2) {
            o[j2][0] *= aR0; o[j2][1] *= aR1; o[j2][2] *= aR2; o[j2][3] *= aR3;
        }
        // (8) P -> LDS, packed b64, wave-private (no barrier needed)
        uint2* pq = (uint2*)(pw + lo * 80);
        #pragma unroll
        for (int j = 0; j < 4; ++j) {
            uint2 d;
            d.x = (unsigned)f2bf(s4[j][0]) | ((unsigned)f2bf(s4[j][1]) << 16);
            d.y = (unsigned)f2bf(s4[j][2]) | ((unsigned)f2bf(s4[j][3]) << 16);
            pq[j * 4 + hi] = d;
        }
        // (9) O += P V
        __builtin_amdgcn_s_setprio(1);
        #pragma unroll
        for (int kk = 0; kk < 2; ++kk) {
            const bf16x8 pf = *(const bf16x8*)(pw + lo * 80 + kk * 32 + hi * 8);
            #pragma unroll
            for (int j2 = 0; j2 < 4; ++j2)
                o[j2] = __builtin_amdgcn_mfma_f32_16x16x32_bf16(
                    pf, vf[kk * 4 + j2], o[j2], 0, 0, 0);
        }
        __builtin_amdgcn_s_setprio(0);
    }

    // ---- epilogue ----
    const float iR0 = 1.0f / __shfl(lsum, hi * 4 + 0);
    const float iR1 = 1.0f / __shfl(lsum, hi * 4 + 1);
    const float iR2 = 1.0f / __shfl(lsum, hi * 4 + 2);
    const float iR3 = 1.0f / __shfl(lsum, hi * 4 + 3);
    const int qC0 = qg * 16 + hi * 4;
    #pragma unroll
    for (int j2 = 0; j2 < 4; ++j2) {
        O[(size_t)(b * 512 + qC0 + 0) * 512 + h * 64 + j2 * 16 + lo] = f2bf(o[j2][0] * iR0);
        O[(size_t)(b * 512 + qC0 + 1) * 512 + h * 64 + j2 * 16 + lo] = f2bf(o[j2][1] * iR1);
        O[(size_t)(b * 512 + qC0 + 2) * 512 + h * 64 + j2 * 16 + lo] = f2bf(o[j2][2] * iR2);
        O[(size_t)(b * 512 + qC0 + 3) * 512 + h * 64 + j2 * 16 + lo] = f2bf(o[j2][3] * iR3);
    }
}

// ---------------- launch ----------------
extern "C" void kernel_launch(void* const* d_in, const int* in_sizes, int n_in,
                              void* d_out, int out_size, void* d_ws, size_t ws_size,
                              hipStream_t stream) {
    const float* x     = (const float*)d_in[0];
    const float* inter = (const float*)d_in[1];
    const float* qkv_w = (const float*)d_in[2];
    const float* qkv_b = (const float*)d_in[3];
    const float* out_w = (const float*)d_in[4];
    const float* out_b = (const float*)d_in[5];
    const float* n1g   = (const float*)d_in[6];
    const float* n1b   = (const float*)d_in[7];
    const float* n2g   = (const float*)d_in[8];
    const float* n2b   = (const float*)d_in[9];
    const float* iw    = (const float*)d_in[10];
    const float* fw1   = (const float*)d_in[11];
    const float* fb1   = (const float*)d_in[12];
    const float* fw2   = (const float*)d_in[13];
    const float* fb2   = (const float*)d_in[14];
    float* out = (float*)d_out;

    // workspace layout (bytes): total 190,840,832
    //   qbuf    @ 0           : 16,777,216  (16384 x 512 bf16 Q)
    //   kfrag   @ 16777216    : 16,777,216  (fragment blobs)
    //   vfrag   @ 33554432    : 16,777,216  (fragment blobs)
    //   attnout @ 50331648    : 16,777,216
    //   x2      @ 67108864    : 33,554,432  (fp32)
    //   h_bf    @ 100663296   : 16,777,216
    //   ffnmid  @ 117440512   : 67,108,864
    //   weights @ 184549376   : ~6.3 MB
    if (ws_size < 190840832ull) return;
    char* ws = (char*)d_ws;
    unsigned short* qbuf    = (unsigned short*)(ws);
    unsigned short* kfrag   = (unsigned short*)(ws + 16777216ull);
    unsigned short* vfrag   = (unsigned short*)(ws + 33554432ull);
    unsigned short* attnout = (unsigned short*)(ws + 50331648ull);
    float*          x2      = (float*)(ws + 67108864ull);
    unsigned short* h_bf    = (unsigned short*)(ws + 100663296ull);
    unsigned short* ffnmid  = (unsigned short*)(ws + 117440512ull);
    unsigned short* qkv_wT  = (unsigned short*)(ws + 184549376ull);
    unsigned short* out_wT  = (unsigned short*)(ws + 186122240ull);
    unsigned short* fw1T    = (unsigned short*)(ws + 186646528ull);
    unsigned short* fw2T    = (unsigned short*)(ws + 188743680ull);

    const int M = BB * LL;  // 16384

    // 0. weight transposes -> bf16 B^T
    transpose_bf16<<<dim3(1536 / 32, 512 / 32), 256, 0, stream>>>(qkv_w, qkv_wT, 512, 1536);
    transpose_bf16<<<dim3(512 / 32, 512 / 32), 256, 0, stream>>>(out_w, out_wT, 512, 512);
    transpose_bf16<<<dim3(2048 / 32, 512 / 32), 256, 0, stream>>>(fw1, fw1T, 512, 2048);
    transpose_bf16<<<dim3(512 / 32, 2048 / 32), 256, 0, stream>>>(fw2, fw2T, 2048, 512);
    // 1. LN1: x -> h_bf
    ln_kernel<<<M, 256, 0, stream>>>(x, n1g, n1b, h_bf);
    // 2. qkv GEMM -> qbuf + kfrag + vfrag (fragment-packed K/V); 1D swizzled grid
    gemm_mfma<0, 0, 2><<<dim3((1536 / 128) * (M / 128)), 256, 0, stream>>>(
        h_bf, qkv_wT, qkv_b, nullptr, qbuf, kfrag, vfrag, M, 1536, 512);
    // 3. fused flash attention (v4 keeper + plds stride fix)
    flash_kernel<<<dim3(LL / 16, BB), 512, 0, stream>>>(qbuf, kfrag, vfrag, inter, iw, attnout);
    // 4. x2 = x + attnout @ out_w + out_b
    gemm_mfma<0, 1, 0><<<dim3((512 / 128) * (M / 128)), 256, 0, stream>>>(
        attnout, out_wT, out_b, x, x2, nullptr, nullptr, M, 512, 512);
    // 5. LN2: x2 -> h_bf
    ln_kernel<<<M, 256, 0, stream>>>(x2, n2g, n2b, h_bf);
    // 6. ffnmid = gelu(h2 @ fw1 + fb1) -> bf16
    gemm_mfma<1, 0, 1><<<dim3((2048 / 128) * (M / 128)), 256, 0, stream>>>(
        h_bf, fw1T, fb1, nullptr, ffnmid, nullptr, nullptr, M, 2048, 512);
    // 7. out = x2 + ffnmid @ fw2 + fb2
    gemm_mfma<0, 1, 0><<<dim3((512 / 128) * (M / 128)), 256, 0, stream>>>(
        ffnmid, fw2T, fb2, x2, out, nullptr, nullptr, M, 512, 2048);
}